// Round 14
// baseline (341.800 us; speedup 1.0000x reference)
//
#include <hip/hip_runtime.h>
#include <hip/hip_bf16.h>

// Net_40089224741482 round 14: consolidation.
//  - r12 GEMM shapes restored (expert 256x256/1024thr separate-majority; r13's
//    appended-tail merge regressed: minority blocks must be scheduled FIRST)
//  - gemm1+gemm5 stay fused ([4096x2048], split bias)
//  - gemm4 (16 blocks of 256x256, Nt=1) merged into the expert dispatch with
//    gemm4 blocks first -> co-resident from t=0, expert backfills (no tail)
//  - dispatches: detect, convert, transpose, g15, g2, g3, dual(g4+expert), final

typedef _Float16 half8 __attribute__((ext_vector_type(8)));
typedef _Float16 half4v __attribute__((ext_vector_type(4)));
typedef float floatx16 __attribute__((ext_vector_type(16)));

namespace {
constexpr int kB = 4096, kS = 128, kA = 32, kH = 1024, kN = 256;
constexpr size_t al(size_t x) { return (x + 255) & ~size_t(255); }
constexpr size_t OFF_FLAG  = 0;
constexpr size_t OFF_S16   = 256;
constexpr size_t OFF_WEXPT = OFF_S16   + al((size_t)kB * kS * 2);
constexpr size_t OFF_WV1T  = OFF_WEXPT + al((size_t)kN * kA * kH * 2);
constexpr size_t OFF_WL1T  = OFF_WV1T  + (size_t)kS * kH * 2;   // contiguous with WV1T
constexpr size_t OFF_WV2T  = OFF_WL1T  + al((size_t)kS * kH * 2);
constexpr size_t OFF_WV3T  = OFF_WV2T  + al((size_t)kH * kH * 2);
constexpr size_t OFF_WV4T  = OFF_WV3T  + al((size_t)kH * kH * 2);
constexpr size_t OFF_BUFC  = OFF_WV4T  + al((size_t)kH * kN * 2);
constexpr size_t OFF_B2V   = OFF_BUFC  + al((size_t)kB * 2 * kH * 2);
constexpr size_t OFF_B3    = OFF_B2V   + al((size_t)kB * kH * 2);
constexpr size_t OFF_VAL   = OFF_B3    + al((size_t)kB * kH * 2);
constexpr size_t OFF_Z     = OFF_VAL   + al((size_t)kB * kN * 4);
} // namespace

__device__ __forceinline__ float ldraw(const void* p, size_t i, int bf) {
    if (bf) return __uint_as_float(((unsigned)((const unsigned short*)p)[i]) << 16);
    return ((const float*)p)[i];
}

__device__ __forceinline__ float4 ldraw4(const void* p, size_t i, int bf) {
    if (bf) {
        ushort4 u = *(const ushort4*)((const unsigned short*)p + i);
        return make_float4(__uint_as_float((unsigned)u.x << 16),
                           __uint_as_float((unsigned)u.y << 16),
                           __uint_as_float((unsigned)u.z << 16),
                           __uint_as_float((unsigned)u.w << 16));
    }
    return *(const float4*)((const float*)p + i);
}

__device__ __forceinline__ void gl_lds16(const _Float16* g, _Float16* l) {
    __builtin_amdgcn_global_load_lds(
        (const __attribute__((address_space(1))) unsigned int*)g,
        (__attribute__((address_space(3))) unsigned int*)l, 16, 0, 0);
}

__device__ __forceinline__ float fast_tanh(float x) {
    x = fminf(9.f, fmaxf(-9.f, x));
    float e = __expf(2.f * x);
    return (e - 1.f) * __builtin_amdgcn_rcpf(e + 1.f);
}

// --- dtype detection, parallel (fp32 low-16 = uniform mantissa; bf16-packed -> exp near 127)
__global__ void detect_kernel(const unsigned int* __restrict__ s_raw, int* __restrict__ flag) {
    __shared__ int cnt;
    if (threadIdx.x == 0) cnt = 0;
    __syncthreads();
    const unsigned e = (s_raw[threadIdx.x] >> 7) & 0xFFu;
    int c = (e >= 118u && e <= 135u) ? 1 : 0;
    for (int off = 32; off > 0; off >>= 1) c += __shfl_down(c, off);
    if ((threadIdx.x & 63) == 0) atomicAdd(&cnt, c);
    __syncthreads();
    if (threadIdx.x == 0) *flag = (cnt > 128) ? 1 : 0;
}

__global__ void convert_to_f16(const void* __restrict__ src, _Float16* __restrict__ dst,
                               int n, const int* __restrict__ flag) {
    const int bf = *flag;
    int i = blockIdx.x * blockDim.x + threadIdx.x;
    const int stride = gridDim.x * blockDim.x;
    for (; i < n; i += stride) dst[i] = (_Float16)ldraw(src, i, bf);
}

// --- ALL weight transposes in one dispatch: src [Z][K][N] -> dst [Z][N][K] f16
struct TDesc { const void* src; _Float16* dst; int K; int N; int tiles; };
struct TPack { TDesc d[6]; };

__global__ void transpose_all(TPack p, const int* __restrict__ flag) {
    __shared__ float tile[32][33];
    const int bf = *flag;
    int bid = blockIdx.x;
    int i = 0;
    while (bid >= p.d[i].tiles) { bid -= p.d[i].tiles; ++i; }
    const int K = p.d[i].K, N = p.d[i].N;
    const int tpz = (N >> 5) * (K >> 5);
    const int z = bid / tpz, r = bid - z * tpz;
    const int n0 = (r % (N >> 5)) * 32, k0 = (r / (N >> 5)) * 32;
    const size_t zo = (size_t)z * K * N;
    const void* src = p.d[i].src;
    _Float16* dst = p.d[i].dst;
    const int tx = threadIdx.x, ty = threadIdx.y;  // tx 0..7, ty 0..31
    float4 v = ldraw4(src, zo + (size_t)(k0 + ty) * N + n0 + tx * 4, bf);
    tile[ty][tx * 4 + 0] = v.x;
    tile[ty][tx * 4 + 1] = v.y;
    tile[ty][tx * 4 + 2] = v.z;
    tile[ty][tx * 4 + 3] = v.w;
    __syncthreads();
    half4v o;
#pragma unroll
    for (int j = 0; j < 4; ++j) o[j] = (_Float16)tile[tx * 4 + j][ty];
    *(half4v*)(dst + zo + (size_t)(n0 + ty) * K + k0 + tx * 4) = o;
}

// --- GEMM argument pack (runtime shape/flags; template fixes tile geometry)
struct GArgs {
    const _Float16* A;
    const _Float16* Bt;
    const void* bias;
    const void* bias2;   // split-bias epilogue (fused gemm1+gemm5)
    void* C;
    int split;           // col < split -> bias[col], else bias2[col-split]
    int N, K, lda, Mt, Nt, relu, of16;
};

// --- core: double-buffered MFMA GEMM, fragment-order LDS, global_load_lds w16,
// XCD swizzle. C[M,N] = act(A[M,K](lda) @ Bt[N,K]^T + bias).
template <int TM, int TN, int WM, int WN>
__device__ __forceinline__ void dgemm_core(const GArgs& g, int bid, const int* flagp) {
    constexpr int NT = WM * WN * 64;
    constexpr int BK = 32;
    constexpr int MI = TM / WM / 32, NI = TN / WN / 32;
    constexpr int ACH = TM * BK / 8;
    constexpr int BCH = TN * BK / 8;
    constexpr int AT = (ACH + NT - 1) / NT;
    constexpr int BT = (BCH + NT - 1) / NT;
    __shared__ _Float16 As[2 * ACH * 8];
    __shared__ _Float16 Bs[2 * BCH * 8];

    const int tid = threadIdx.x;
    const int lane = tid & 63;
    const int w = tid >> 6, wr = w / WN, wc = w % WN;
    const int N = g.N, K = g.K, lda = g.lda;

    int mt, nt;
    if ((g.Mt & 7) == 0 && (g.Nt & 7) == 0) {
        const int xcd = bid & 7, loc = bid >> 3;
        const int Bn = g.Nt >> 3;
        const int sr = loc / (8 * Bn);
        const int rem = loc - sr * (8 * Bn);
        mt = sr * 8 + (rem & 7);
        nt = xcd * Bn + (rem >> 3);
    } else {
        mt = bid % g.Mt;
        nt = bid / g.Mt;
    }
    const int m0 = mt * TM, n0 = nt * TN;

    const _Float16* gAsrc[AT];
    _Float16* lAdst[AT];
#pragma unroll
    for (int t = 0; t < AT; ++t) {
        int c = t * NT + tid;
        if (c >= ACH) c = ACH - 1;
        const int ks = c / (TM * 2), rem = c % (TM * 2);
        const int row = (rem >> 6) * 32 + (rem & 31);
        const int kcol = ks * 16 + ((rem >> 5) & 1) * 8;
        gAsrc[t] = g.A + (size_t)(m0 + row) * lda + kcol;
        lAdst[t] = As + c * 8;
    }
    const _Float16* gBsrc[BT];
    _Float16* lBdst[BT];
#pragma unroll
    for (int t = 0; t < BT; ++t) {
        int c = t * NT + tid;
        if (c >= BCH) c = BCH - 1;
        const int ks = c / (TN * 2), rem = c % (TN * 2);
        const int row = (rem >> 6) * 32 + (rem & 31);
        const int kcol = ks * 16 + ((rem >> 5) & 1) * 8;
        gBsrc[t] = g.Bt + (size_t)(n0 + row) * K + kcol;
        lBdst[t] = Bs + c * 8;
    }

    auto issue = [&](int k0, int st) {
#pragma unroll
        for (int t = 0; t < AT; ++t)
            if ((t + 1) * NT <= ACH || t * NT + tid < ACH)
                gl_lds16(gAsrc[t] + k0, lAdst[t] + st * ACH * 8);
#pragma unroll
        for (int t = 0; t < BT; ++t)
            if ((t + 1) * NT <= BCH || t * NT + tid < BCH)
                gl_lds16(gBsrc[t] + k0, lBdst[t] + st * BCH * 8);
    };

    floatx16 acc[MI][NI];
#pragma unroll
    for (int mi = 0; mi < MI; ++mi)
#pragma unroll
        for (int ni = 0; ni < NI; ++ni)
#pragma unroll
            for (int i = 0; i < 16; ++i) acc[mi][ni][i] = 0.f;

    auto compute = [&](int st) {
#pragma unroll
        for (int ks = 0; ks < 2; ++ks) {
            half8 af[MI], bf[NI];
#pragma unroll
            for (int mi = 0; mi < MI; ++mi)
                af[mi] = *(const half8*)(As + st * ACH * 8 + ((size_t)(ks * TM * 2 + (wr * MI + mi) * 64 + lane)) * 8);
#pragma unroll
            for (int ni = 0; ni < NI; ++ni)
                bf[ni] = *(const half8*)(Bs + st * BCH * 8 + ((size_t)(ks * TN * 2 + (wc * NI + ni) * 64 + lane)) * 8);
#pragma unroll
            for (int mi = 0; mi < MI; ++mi)
#pragma unroll
                for (int ni = 0; ni < NI; ++ni)
                    acc[mi][ni] = __builtin_amdgcn_mfma_f32_32x32x16_f16(af[mi], bf[ni], acc[mi][ni], 0, 0, 0);
        }
    };

    issue(0, 0);
    for (int k0 = 0; k0 < K; k0 += 2 * BK) {
        __syncthreads();
        if (k0 + BK < K) issue(k0 + BK, 1);
        compute(0);
        __syncthreads();
        if (k0 + 2 * BK < K) issue(k0 + 2 * BK, 0);
        compute(1);
    }

    const int bf_ = *flagp;
    const int am = lane & 31;
    const int half = lane >> 5;
#pragma unroll
    for (int mi = 0; mi < MI; ++mi)
#pragma unroll
        for (int ni = 0; ni < NI; ++ni) {
            const int Rb = m0 + (wr * MI + mi) * 32;
            const int Cb = n0 + (wc * NI + ni) * 32 + am;
            const float bv = (Cb < g.split) ? ldraw(g.bias, Cb, bf_)
                                            : ldraw(g.bias2, Cb - g.split, bf_);
#pragma unroll
            for (int rr = 0; rr < 16; ++rr) {
                const int row = Rb + (rr & 3) + 8 * (rr >> 2) + 4 * half;
                float x = acc[mi][ni][rr] + bv;
                if (g.relu) x = fmaxf(x, 0.f);
                if (g.of16) ((_Float16*)g.C)[(size_t)row * N + Cb] = (_Float16)x;
                else ((float*)g.C)[(size_t)row * N + Cb] = x;
            }
        }
}

template <int TM, int TN, int WM, int WN>
__launch_bounds__(WM * WN * 64, 2)
__global__ void dgemm_one(GArgs g, const int* __restrict__ flagp) {
    dgemm_core<TM, TN, WM, WN>(g, blockIdx.x, flagp);
}

// two independent GEMMs in one dispatch; minority FIRST: bid<nb0 -> g0
template <int TM, int TN, int WM, int WN>
__launch_bounds__(WM * WN * 64, 2)
__global__ void dgemm_dual(GArgs g0, GArgs g1, int nb0, const int* __restrict__ flagp) {
    const int bid = blockIdx.x;
    if (bid < nb0) dgemm_core<TM, TN, WM, WN>(g0, bid, flagp);
    else           dgemm_core<TM, TN, WM, WN>(g1, bid - nb0, flagp);
}

// --- fused: tanh(z) -> ||c-a|| -> softmax(-dist) . values, one block per b
// NOTE: z already includes the bexp bias (added in the expert GEMM epilogue).
__launch_bounds__(256)
__global__ void final_fused(const _Float16* __restrict__ z, const void* __restrict__ a_raw,
                            const float* __restrict__ values, const int* __restrict__ flag,
                            void* __restrict__ out) {
    const int b = blockIdx.x;
    const int n = threadIdx.x;
    const int bf = *flag;
    __shared__ float as_[32];
    if (n < 32) as_[n] = ldraw(a_raw, (size_t)b * kA + n, bf);
    __syncthreads();

    const _Float16* zp = z + (size_t)b * (kN * kA) + n * kA;
    float zl[32];
#pragma unroll
    for (int t = 0; t < 4; ++t) {
        half8 h = *(const half8*)(zp + t * 8);
#pragma unroll
        for (int j = 0; j < 8; ++j) zl[t * 8 + j] = (float)h[j];
    }
    float sum = 0.f;
#pragma unroll
    for (int a = 0; a < 32; ++a) {
        const float c = fast_tanh(zl[a]);  // MAX_A=1; bexp already in z
        const float d = c - as_[a];
        sum = fmaf(d, d, sum);
    }
    const float dist = sqrtf(sum + 0.01f);
    const float v = values[(size_t)b * kN + n];

    const int wid = n >> 6, lane = n & 63;
    __shared__ float red[8];
    __shared__ float rw[4], rwv[4];
    float m = dist;
    for (int off = 32; off > 0; off >>= 1) m = fminf(m, __shfl_down(m, off));
    if (lane == 0) red[wid] = m;
    __syncthreads();
    if (n == 0) red[4] = fminf(fminf(red[0], red[1]), fminf(red[2], red[3]));
    __syncthreads();
    const float dmin = red[4];

    float wgt = expf(dmin - dist);
    float wv = wgt * v;
    for (int off = 32; off > 0; off >>= 1) {
        wgt += __shfl_down(wgt, off);
        wv += __shfl_down(wv, off);
    }
    if (lane == 0) { rw[wid] = wgt; rwv[wid] = wv; }
    __syncthreads();
    if (n == 0) {
        const float sw = rw[0] + rw[1] + rw[2] + rw[3];
        const float swv = rwv[0] + rwv[1] + rwv[2] + rwv[3];
        const float o = swv / sw;
        if (bf) ((__hip_bfloat16*)out)[b] = __float2bfloat16(o);
        else    ((float*)out)[b] = o;
    }
}

extern "C" void kernel_launch(void* const* d_in, const int* in_sizes, int n_in,
                              void* d_out, int out_size, void* d_ws, size_t ws_size,
                              hipStream_t stream) {
    (void)in_sizes; (void)n_in; (void)out_size; (void)ws_size;
    char* ws = (char*)d_ws;
    int* flag = (int*)(ws + OFF_FLAG);
    _Float16* s16   = (_Float16*)(ws + OFF_S16);
    _Float16* wexpt = (_Float16*)(ws + OFF_WEXPT);
    _Float16* wv1t  = (_Float16*)(ws + OFF_WV1T);  // wl1t contiguous after -> [2048x128]
    _Float16* wl1t  = (_Float16*)(ws + OFF_WL1T);
    _Float16* wv2t  = (_Float16*)(ws + OFF_WV2T);
    _Float16* wv3t  = (_Float16*)(ws + OFF_WV3T);
    _Float16* wv4t  = (_Float16*)(ws + OFF_WV4T);
    _Float16* bufC  = (_Float16*)(ws + OFF_BUFC);  // [4096 x 2048]: h1 | hloc
    _Float16* b2v   = (_Float16*)(ws + OFF_B2V);
    _Float16* b3    = (_Float16*)(ws + OFF_B3);
    float* values   = (float*)(ws + OFF_VAL);
    _Float16* z     = (_Float16*)(ws + OFF_Z);

    detect_kernel<<<1, 256, 0, stream>>>((const unsigned int*)d_in[0], flag);
    convert_to_f16<<<512, 256, 0, stream>>>(d_in[0], s16, kB * kS, flag);

    TPack tp;
    tp.d[0] = {d_in[2],  wv1t,  kS, kH, (kH / 32) * (kS / 32)};          // 128
    tp.d[1] = {d_in[10], wl1t,  kS, kH, (kH / 32) * (kS / 32)};          // 128
    tp.d[2] = {d_in[4],  wv2t,  kH, kH, (kH / 32) * (kH / 32)};          // 1024
    tp.d[3] = {d_in[6],  wv3t,  kH, kH, (kH / 32) * (kH / 32)};          // 1024
    tp.d[4] = {d_in[8],  wv4t,  kH, kN, (kN / 32) * (kH / 32)};          // 256
    tp.d[5] = {d_in[12], wexpt, kH, kA, kN * (kA / 32) * (kH / 32)};     // 8192
    int total_tiles = 0;
    for (int i = 0; i < 6; ++i) total_tiles += tp.d[i].tiles;            // 10752
    transpose_all<<<total_tiles, dim3(8, 32), 0, stream>>>(tp, flag);

    const int BIG = 1 << 30;
    // fused gemm1+gemm5: bufC[4096x2048] = relu(s16 @ [wv1t;wl1t]^T + [bv1;bl1])
    {
        GArgs g{s16, wv1t, d_in[3], d_in[11], bufC, kH,
                2 * kH, kS, kS, kB / 64, (2 * kH) / 64, 1, 1};
        dgemm_one<64, 64, 2, 2><<<(kB / 64) * ((2 * kH) / 64), 256, 0, stream>>>(g, flag);
    }
    // gemm2: b2v = relu(bufC[:, :1024] @ wv2t^T + bv2)
    {
        GArgs g{bufC, wv2t, d_in[5], d_in[5], b2v, BIG,
                kH, kH, 2 * kH, kB / 128, kH / 128, 1, 1};
        dgemm_one<128, 128, 2, 2><<<(kB / 128) * (kH / 128), 256, 0, stream>>>(g, flag);
    }
    // gemm3: b3 = relu(b2v @ wv3t^T + bv3)
    {
        GArgs g{b2v, wv3t, d_in[7], d_in[7], b3, BIG,
                kH, kH, kH, kB / 128, kH / 128, 1, 1};
        dgemm_one<128, 128, 2, 2><<<(kB / 128) * (kH / 128), 256, 0, stream>>>(g, flag);
    }
    // dual: gemm4 (16 blocks, FIRST) + expert (512 blocks)
    {
        GArgs g4{b3, wv4t, d_in[9], d_in[9], values, BIG,
                 kN, kH, kH, kB / 256, kN / 256, 0, 0};
        GArgs ge{bufC + kH, wexpt, d_in[13], d_in[13], z, BIG,
                 kN * kA, kH, 2 * kH, kB / 256, (kN * kA) / 256, 0, 1};
        const int nb4 = (kB / 256) * (kN / 256);          // 16
        const int nbe = (kB / 256) * ((kN * kA) / 256);   // 512
        dgemm_dual<256, 256, 4, 4><<<nb4 + nbe, 1024, 0, stream>>>(g4, ge, nb4, flag);
    }
    // fused tanh + distance + softmax + value readout
    final_fused<<<kB, 256, 0, stream>>>(z, d_in[1], values, flag, d_out);
}

// Round 15
// 314.805 us; speedup vs baseline: 1.0858x; 1.0858x over previous
//
#include <hip/hip_runtime.h>
#include <hip/hip_bf16.h>

// Net_40089224741482 round 15: consolidation to best-known parts.
//  - expert GEMM alone again (r12 config 256x256/1024thr, 110us) — r13/r14 proved
//    co-dispatching anything with it costs ~40us regardless of block order
//  - gemm1+gemm5 stay fused ([4096x2048] 64x64, split bias) — never regressed
//  - convert_to_f16 merged into transpose_all (K=0 sentinel = straight copy)
//  - dispatches: detect, trans+conv, g15, g2, g3, g4, expert, final  (8 total)

typedef _Float16 half8 __attribute__((ext_vector_type(8)));
typedef _Float16 half4v __attribute__((ext_vector_type(4)));
typedef float floatx16 __attribute__((ext_vector_type(16)));

namespace {
constexpr int kB = 4096, kS = 128, kA = 32, kH = 1024, kN = 256;
constexpr size_t al(size_t x) { return (x + 255) & ~size_t(255); }
constexpr size_t OFF_FLAG  = 0;
constexpr size_t OFF_S16   = 256;
constexpr size_t OFF_WEXPT = OFF_S16   + al((size_t)kB * kS * 2);
constexpr size_t OFF_WV1T  = OFF_WEXPT + al((size_t)kN * kA * kH * 2);
constexpr size_t OFF_WL1T  = OFF_WV1T  + (size_t)kS * kH * 2;   // contiguous with WV1T
constexpr size_t OFF_WV2T  = OFF_WL1T  + al((size_t)kS * kH * 2);
constexpr size_t OFF_WV3T  = OFF_WV2T  + al((size_t)kH * kH * 2);
constexpr size_t OFF_WV4T  = OFF_WV3T  + al((size_t)kH * kH * 2);
constexpr size_t OFF_BUFC  = OFF_WV4T  + al((size_t)kH * kN * 2);
constexpr size_t OFF_B2V   = OFF_BUFC  + al((size_t)kB * 2 * kH * 2);
constexpr size_t OFF_B3    = OFF_B2V   + al((size_t)kB * kH * 2);
constexpr size_t OFF_VAL   = OFF_B3    + al((size_t)kB * kH * 2);
constexpr size_t OFF_Z     = OFF_VAL   + al((size_t)kB * kN * 4);
} // namespace

__device__ __forceinline__ float ldraw(const void* p, size_t i, int bf) {
    if (bf) return __uint_as_float(((unsigned)((const unsigned short*)p)[i]) << 16);
    return ((const float*)p)[i];
}

__device__ __forceinline__ float4 ldraw4(const void* p, size_t i, int bf) {
    if (bf) {
        ushort4 u = *(const ushort4*)((const unsigned short*)p + i);
        return make_float4(__uint_as_float((unsigned)u.x << 16),
                           __uint_as_float((unsigned)u.y << 16),
                           __uint_as_float((unsigned)u.z << 16),
                           __uint_as_float((unsigned)u.w << 16));
    }
    return *(const float4*)((const float*)p + i);
}

__device__ __forceinline__ void gl_lds16(const _Float16* g, _Float16* l) {
    __builtin_amdgcn_global_load_lds(
        (const __attribute__((address_space(1))) unsigned int*)g,
        (__attribute__((address_space(3))) unsigned int*)l, 16, 0, 0);
}

__device__ __forceinline__ float fast_tanh(float x) {
    x = fminf(9.f, fmaxf(-9.f, x));
    float e = __expf(2.f * x);
    return (e - 1.f) * __builtin_amdgcn_rcpf(e + 1.f);
}

// --- dtype detection, parallel (fp32 low-16 = uniform mantissa; bf16-packed -> exp near 127)
__global__ void detect_kernel(const unsigned int* __restrict__ s_raw, int* __restrict__ flag) {
    __shared__ int cnt;
    if (threadIdx.x == 0) cnt = 0;
    __syncthreads();
    const unsigned e = (s_raw[threadIdx.x] >> 7) & 0xFFu;
    int c = (e >= 118u && e <= 135u) ? 1 : 0;
    for (int off = 32; off > 0; off >>= 1) c += __shfl_down(c, off);
    if ((threadIdx.x & 63) == 0) atomicAdd(&cnt, c);
    __syncthreads();
    if (threadIdx.x == 0) *flag = (cnt > 128) ? 1 : 0;
}

// --- ALL weight transposes + the s->f16 convert in ONE dispatch.
// K>0: src [Z][K][N] -> dst [Z][N][K] f16 (32x32 tiles).
// K==0: straight elementwise convert, 4096 elems/block (N = total elements).
struct TDesc { const void* src; _Float16* dst; int K; int N; int tiles; };
struct TPack { TDesc d[7]; };

__global__ void transpose_all(TPack p, const int* __restrict__ flag) {
    __shared__ float tile[32][33];
    const int bf = *flag;
    int bid = blockIdx.x;
    int i = 0;
    while (bid >= p.d[i].tiles) { bid -= p.d[i].tiles; ++i; }
    const void* src = p.d[i].src;
    _Float16* dst = p.d[i].dst;
    const int tx = threadIdx.x, ty = threadIdx.y;  // tx 0..7, ty 0..31
    const int K = p.d[i].K, N = p.d[i].N;
    if (K == 0) {  // straight convert
        const int lin = ty * 8 + tx;
        const size_t base = (size_t)bid * 4096;
#pragma unroll
        for (int t = 0; t < 4; ++t) {
            const size_t idx = base + (size_t)t * 1024 + (size_t)lin * 4;
            float4 v = ldraw4(src, idx, bf);
            half4v o = {(_Float16)v.x, (_Float16)v.y, (_Float16)v.z, (_Float16)v.w};
            *(half4v*)(dst + idx) = o;
        }
        return;
    }
    const int tpz = (N >> 5) * (K >> 5);
    const int z = bid / tpz, r = bid - z * tpz;
    const int n0 = (r % (N >> 5)) * 32, k0 = (r / (N >> 5)) * 32;
    const size_t zo = (size_t)z * K * N;
    float4 v = ldraw4(src, zo + (size_t)(k0 + ty) * N + n0 + tx * 4, bf);
    tile[ty][tx * 4 + 0] = v.x;
    tile[ty][tx * 4 + 1] = v.y;
    tile[ty][tx * 4 + 2] = v.z;
    tile[ty][tx * 4 + 3] = v.w;
    __syncthreads();
    half4v o;
#pragma unroll
    for (int j = 0; j < 4; ++j) o[j] = (_Float16)tile[tx * 4 + j][ty];
    *(half4v*)(dst + zo + (size_t)(n0 + ty) * K + k0 + tx * 4) = o;
}

// --- GEMM argument pack (runtime shape/flags; template fixes tile geometry)
struct GArgs {
    const _Float16* A;
    const _Float16* Bt;
    const void* bias;
    const void* bias2;   // split-bias epilogue (fused gemm1+gemm5)
    void* C;
    int split;           // col < split -> bias[col], else bias2[col-split]
    int N, K, lda, Mt, Nt, relu, of16;
};

// --- core: double-buffered MFMA GEMM, fragment-order LDS, global_load_lds w16,
// XCD swizzle. C[M,N] = act(A[M,K](lda) @ Bt[N,K]^T + bias).
template <int TM, int TN, int WM, int WN>
__device__ __forceinline__ void dgemm_core(const GArgs& g, int bid, const int* flagp) {
    constexpr int NT = WM * WN * 64;
    constexpr int BK = 32;
    constexpr int MI = TM / WM / 32, NI = TN / WN / 32;
    constexpr int ACH = TM * BK / 8;
    constexpr int BCH = TN * BK / 8;
    constexpr int AT = (ACH + NT - 1) / NT;
    constexpr int BT = (BCH + NT - 1) / NT;
    __shared__ _Float16 As[2 * ACH * 8];
    __shared__ _Float16 Bs[2 * BCH * 8];

    const int tid = threadIdx.x;
    const int lane = tid & 63;
    const int w = tid >> 6, wr = w / WN, wc = w % WN;
    const int N = g.N, K = g.K, lda = g.lda;

    int mt, nt;
    if ((g.Mt & 7) == 0 && (g.Nt & 7) == 0) {
        const int xcd = bid & 7, loc = bid >> 3;
        const int Bn = g.Nt >> 3;
        const int sr = loc / (8 * Bn);
        const int rem = loc - sr * (8 * Bn);
        mt = sr * 8 + (rem & 7);
        nt = xcd * Bn + (rem >> 3);
    } else {
        mt = bid % g.Mt;
        nt = bid / g.Mt;
    }
    const int m0 = mt * TM, n0 = nt * TN;

    const _Float16* gAsrc[AT];
    _Float16* lAdst[AT];
#pragma unroll
    for (int t = 0; t < AT; ++t) {
        int c = t * NT + tid;
        if (c >= ACH) c = ACH - 1;
        const int ks = c / (TM * 2), rem = c % (TM * 2);
        const int row = (rem >> 6) * 32 + (rem & 31);
        const int kcol = ks * 16 + ((rem >> 5) & 1) * 8;
        gAsrc[t] = g.A + (size_t)(m0 + row) * lda + kcol;
        lAdst[t] = As + c * 8;
    }
    const _Float16* gBsrc[BT];
    _Float16* lBdst[BT];
#pragma unroll
    for (int t = 0; t < BT; ++t) {
        int c = t * NT + tid;
        if (c >= BCH) c = BCH - 1;
        const int ks = c / (TN * 2), rem = c % (TN * 2);
        const int row = (rem >> 6) * 32 + (rem & 31);
        const int kcol = ks * 16 + ((rem >> 5) & 1) * 8;
        gBsrc[t] = g.Bt + (size_t)(n0 + row) * K + kcol;
        lBdst[t] = Bs + c * 8;
    }

    auto issue = [&](int k0, int st) {
#pragma unroll
        for (int t = 0; t < AT; ++t)
            if ((t + 1) * NT <= ACH || t * NT + tid < ACH)
                gl_lds16(gAsrc[t] + k0, lAdst[t] + st * ACH * 8);
#pragma unroll
        for (int t = 0; t < BT; ++t)
            if ((t + 1) * NT <= BCH || t * NT + tid < BCH)
                gl_lds16(gBsrc[t] + k0, lBdst[t] + st * BCH * 8);
    };

    floatx16 acc[MI][NI];
#pragma unroll
    for (int mi = 0; mi < MI; ++mi)
#pragma unroll
        for (int ni = 0; ni < NI; ++ni)
#pragma unroll
            for (int i = 0; i < 16; ++i) acc[mi][ni][i] = 0.f;

    auto compute = [&](int st) {
#pragma unroll
        for (int ks = 0; ks < 2; ++ks) {
            half8 af[MI], bf[NI];
#pragma unroll
            for (int mi = 0; mi < MI; ++mi)
                af[mi] = *(const half8*)(As + st * ACH * 8 + ((size_t)(ks * TM * 2 + (wr * MI + mi) * 64 + lane)) * 8);
#pragma unroll
            for (int ni = 0; ni < NI; ++ni)
                bf[ni] = *(const half8*)(Bs + st * BCH * 8 + ((size_t)(ks * TN * 2 + (wc * NI + ni) * 64 + lane)) * 8);
#pragma unroll
            for (int mi = 0; mi < MI; ++mi)
#pragma unroll
                for (int ni = 0; ni < NI; ++ni)
                    acc[mi][ni] = __builtin_amdgcn_mfma_f32_32x32x16_f16(af[mi], bf[ni], acc[mi][ni], 0, 0, 0);
        }
    };

    issue(0, 0);
    for (int k0 = 0; k0 < K; k0 += 2 * BK) {
        __syncthreads();
        if (k0 + BK < K) issue(k0 + BK, 1);
        compute(0);
        __syncthreads();
        if (k0 + 2 * BK < K) issue(k0 + 2 * BK, 0);
        compute(1);
    }

    const int bf_ = *flagp;
    const int am = lane & 31;
    const int half = lane >> 5;
#pragma unroll
    for (int mi = 0; mi < MI; ++mi)
#pragma unroll
        for (int ni = 0; ni < NI; ++ni) {
            const int Rb = m0 + (wr * MI + mi) * 32;
            const int Cb = n0 + (wc * NI + ni) * 32 + am;
            const float bv = (Cb < g.split) ? ldraw(g.bias, Cb, bf_)
                                            : ldraw(g.bias2, Cb - g.split, bf_);
#pragma unroll
            for (int rr = 0; rr < 16; ++rr) {
                const int row = Rb + (rr & 3) + 8 * (rr >> 2) + 4 * half;
                float x = acc[mi][ni][rr] + bv;
                if (g.relu) x = fmaxf(x, 0.f);
                if (g.of16) ((_Float16*)g.C)[(size_t)row * N + Cb] = (_Float16)x;
                else ((float*)g.C)[(size_t)row * N + Cb] = x;
            }
        }
}

template <int TM, int TN, int WM, int WN>
__launch_bounds__(WM * WN * 64, 2)
__global__ void dgemm_one(GArgs g, const int* __restrict__ flagp) {
    dgemm_core<TM, TN, WM, WN>(g, blockIdx.x, flagp);
}

// --- fused: tanh(z) -> ||c-a|| -> softmax(-dist) . values, one block per b
// NOTE: z already includes the bexp bias (added in the expert GEMM epilogue).
__launch_bounds__(256)
__global__ void final_fused(const _Float16* __restrict__ z, const void* __restrict__ a_raw,
                            const float* __restrict__ values, const int* __restrict__ flag,
                            void* __restrict__ out) {
    const int b = blockIdx.x;
    const int n = threadIdx.x;
    const int bf = *flag;
    __shared__ float as_[32];
    if (n < 32) as_[n] = ldraw(a_raw, (size_t)b * kA + n, bf);
    __syncthreads();

    const _Float16* zp = z + (size_t)b * (kN * kA) + n * kA;
    float zl[32];
#pragma unroll
    for (int t = 0; t < 4; ++t) {
        half8 h = *(const half8*)(zp + t * 8);
#pragma unroll
        for (int j = 0; j < 8; ++j) zl[t * 8 + j] = (float)h[j];
    }
    float sum = 0.f;
#pragma unroll
    for (int a = 0; a < 32; ++a) {
        const float c = fast_tanh(zl[a]);  // MAX_A=1; bexp already in z
        const float d = c - as_[a];
        sum = fmaf(d, d, sum);
    }
    const float dist = sqrtf(sum + 0.01f);
    const float v = values[(size_t)b * kN + n];

    const int wid = n >> 6, lane = n & 63;
    __shared__ float red[8];
    __shared__ float rw[4], rwv[4];
    float m = dist;
    for (int off = 32; off > 0; off >>= 1) m = fminf(m, __shfl_down(m, off));
    if (lane == 0) red[wid] = m;
    __syncthreads();
    if (n == 0) red[4] = fminf(fminf(red[0], red[1]), fminf(red[2], red[3]));
    __syncthreads();
    const float dmin = red[4];

    float wgt = expf(dmin - dist);
    float wv = wgt * v;
    for (int off = 32; off > 0; off >>= 1) {
        wgt += __shfl_down(wgt, off);
        wv += __shfl_down(wv, off);
    }
    if (lane == 0) { rw[wid] = wgt; rwv[wid] = wv; }
    __syncthreads();
    if (n == 0) {
        const float sw = rw[0] + rw[1] + rw[2] + rw[3];
        const float swv = rwv[0] + rwv[1] + rwv[2] + rwv[3];
        const float o = swv / sw;
        if (bf) ((__hip_bfloat16*)out)[b] = __float2bfloat16(o);
        else    ((float*)out)[b] = o;
    }
}

extern "C" void kernel_launch(void* const* d_in, const int* in_sizes, int n_in,
                              void* d_out, int out_size, void* d_ws, size_t ws_size,
                              hipStream_t stream) {
    (void)in_sizes; (void)n_in; (void)out_size; (void)ws_size;
    char* ws = (char*)d_ws;
    int* flag = (int*)(ws + OFF_FLAG);
    _Float16* s16   = (_Float16*)(ws + OFF_S16);
    _Float16* wexpt = (_Float16*)(ws + OFF_WEXPT);
    _Float16* wv1t  = (_Float16*)(ws + OFF_WV1T);  // wl1t contiguous after -> [2048x128]
    _Float16* wl1t  = (_Float16*)(ws + OFF_WL1T);
    _Float16* wv2t  = (_Float16*)(ws + OFF_WV2T);
    _Float16* wv3t  = (_Float16*)(ws + OFF_WV3T);
    _Float16* wv4t  = (_Float16*)(ws + OFF_WV4T);
    _Float16* bufC  = (_Float16*)(ws + OFF_BUFC);  // [4096 x 2048]: h1 | hloc
    _Float16* b2v   = (_Float16*)(ws + OFF_B2V);
    _Float16* b3    = (_Float16*)(ws + OFF_B3);
    float* values   = (float*)(ws + OFF_VAL);
    _Float16* z     = (_Float16*)(ws + OFF_Z);

    detect_kernel<<<1, 256, 0, stream>>>((const unsigned int*)d_in[0], flag);

    TPack tp;
    tp.d[0] = {d_in[2],  wv1t,  kS, kH, (kH / 32) * (kS / 32)};          // 128
    tp.d[1] = {d_in[10], wl1t,  kS, kH, (kH / 32) * (kS / 32)};          // 128
    tp.d[2] = {d_in[4],  wv2t,  kH, kH, (kH / 32) * (kH / 32)};          // 1024
    tp.d[3] = {d_in[6],  wv3t,  kH, kH, (kH / 32) * (kH / 32)};          // 1024
    tp.d[4] = {d_in[8],  wv4t,  kH, kN, (kN / 32) * (kH / 32)};          // 256
    tp.d[5] = {d_in[12], wexpt, kH, kA, kN * (kA / 32) * (kH / 32)};     // 8192
    tp.d[6] = {d_in[0],  s16,   0,  kB * kS, (kB * kS) / 4096};          // 128 (convert)
    int total_tiles = 0;
    for (int i = 0; i < 7; ++i) total_tiles += tp.d[i].tiles;            // 10880
    transpose_all<<<total_tiles, dim3(8, 32), 0, stream>>>(tp, flag);

    const int BIG = 1 << 30;
    // fused gemm1+gemm5: bufC[4096x2048] = relu(s16 @ [wv1t;wl1t]^T + [bv1;bl1])
    {
        GArgs g{s16, wv1t, d_in[3], d_in[11], bufC, kH,
                2 * kH, kS, kS, kB / 64, (2 * kH) / 64, 1, 1};
        dgemm_one<64, 64, 2, 2><<<(kB / 64) * ((2 * kH) / 64), 256, 0, stream>>>(g, flag);
    }
    // gemm2: b2v = relu(bufC[:, :1024] @ wv2t^T + bv2)
    {
        GArgs g{bufC, wv2t, d_in[5], d_in[5], b2v, BIG,
                kH, kH, 2 * kH, kB / 128, kH / 128, 1, 1};
        dgemm_one<128, 128, 2, 2><<<(kB / 128) * (kH / 128), 256, 0, stream>>>(g, flag);
    }
    // gemm3: b3 = relu(b2v @ wv3t^T + bv3)
    {
        GArgs g{b2v, wv3t, d_in[7], d_in[7], b3, BIG,
                kH, kH, kH, kB / 128, kH / 128, 1, 1};
        dgemm_one<128, 128, 2, 2><<<(kB / 128) * (kH / 128), 256, 0, stream>>>(g, flag);
    }
    // gemm4: values = b3 @ wv4t^T + bv4 (f32 out)
    {
        GArgs g{b3, wv4t, d_in[9], d_in[9], values, BIG,
                kN, kH, kH, kB / 64, kN / 64, 0, 0};
        dgemm_one<64, 64, 2, 2><<<(kB / 64) * (kN / 64), 256, 0, stream>>>(g, flag);
    }
    // expert heads: z = bufC[:, 1024:] @ wexpt^T + bexp (256x256, 1024 thr — ALONE)
    {
        GArgs g{bufC + kH, wexpt, d_in[13], d_in[13], z, BIG,
                kN * kA, kH, 2 * kH, kB / 256, (kN * kA) / 256, 0, 1};
        dgemm_one<256, 256, 4, 4><<<(kB / 256) * ((kN * kA) / 256), 1024, 0, stream>>>(g, flag);
    }
    // fused tanh + distance + softmax + value readout
    final_fused<<<kB, 256, 0, stream>>>(z, d_in[1], values, flag, d_out);
}